// Round 1
// baseline (272.296 us; speedup 1.0000x reference)
//
#include <hip/hip_runtime.h>

// cost[b,dd,i,j,c,uv] = (bounds? x[b,c,uv, i+d*(4-u), j+d*(4-v)] :0) * mask[b,uv,i,j]
// d = dd-4, u=uv/9, v=uv%9.  out = cost (b,D,h,w,c*81+uv) flat, then ctr = x[:,:,40,:,:].

#define NAA 81
#define H 96
#define W 96
#define NC 4
#define ND 9
#define PLANE 9216          // 96*96
#define CHUNK 108           // rows (c*81+uv) per block
#define LSTR 97             // LDS row stride (pad 96 -> 97, conflict-free)
#define WITHIN 324          // NC*81, fast output dim
#define OUTROW 31104        // W*WITHIN
#define CTR_OFF 53747712LL  // 2*9*96*96*324

__global__ __launch_bounds__(512)
void build_cost_kernel(const float* __restrict__ x, const float* __restrict__ mask,
                       float* __restrict__ out) {
    __shared__ float xs[CHUNK * LSTR];   // staged x*mask products  (41,904 B)
    __shared__ int   xbT[CHUNK];         // x row base (or -1 if row OOB)
    __shared__ int   mbT[CHUNK];         // mask row base
    __shared__ int   shT[CHUNK];         // column shift d*(4-v)
    __shared__ unsigned sh4[27];         // shifts+16 packed 4x u8 per within-quad

    const int ii  = blockIdx.x;          // spatial row i
    const int dd  = blockIdx.y;          // disparity index
    const int zz  = blockIdx.z;          // b*3 + chunk
    const int b   = zz / 3;
    const int k   = zz - 3 * b;          // chunk 0..2
    const int d   = dd - 4;
    const int tid = threadIdx.x;

    // ---- phase 0: per-row LUTs for rows [108k, 108k+108) ----
    if (tid < CHUNK) {
        int row = CHUNK * k + tid;       // row = c*81 + uv
        int c  = row / 81;
        int uv = row - 81 * c;
        int u  = uv / 9;
        int v  = uv - 9 * u;
        int ri = ii + d * (4 - u);
        int xb = ((b * NC + c) * NAA + uv) * PLANE + ri * W;
        xbT[tid] = ((unsigned)ri < (unsigned)H) ? xb : -1;
        mbT[tid] = ((b * NAA + uv) * H + ii) * W;
        shT[tid] = d * (4 - v);
    }
    if (tid < 27) {
        unsigned p = 0;
        #pragma unroll
        for (int w = 0; w < 4; ++w) {
            int within = CHUNK * k + 4 * tid + w;
            int uv = within % 81;
            int v  = uv % 9;
            p |= (unsigned)(d * (4 - v) + 16) << (8 * w);
        }
        sh4[tid] = p;
    }
    __syncthreads();

    // ---- phase 1: stage xs[rl][col] = x[row, ri, col] * mask[uv, ii, col - sh] ----
    // coalesced global reads along col; conflict-free LDS writes (lane delta 1)
    for (int idx = tid; idx < CHUNK * 24; idx += 512) {
        int rl = idx / 24;
        int cq = idx - rl * 24;
        int xb = xbT[rl];
        int mb = mbT[rl];
        int sh = shT[rl];
        int xbc = max(xb, 0);
        float* lrow = xs + rl * LSTR;
        #pragma unroll
        for (int g = 0; g < 4; ++g) {
            int col = cq + 24 * g;
            float xv = x[xbc + col];
            int jm = col - sh;                       // output j this cell feeds
            float mv = mask[mb + min(max(jm, 0), W - 1)];
            float val = ((unsigned)jm < (unsigned)W && xb >= 0) ? xv * mv : 0.0f;
            lrow[col] = val;
        }
    }
    __syncthreads();

    // ---- phase 2: coalesced float4 stores in output order ----
    const size_t gbase = (size_t)((b * ND + dd) * H + ii) * OUTROW + CHUNK * k;
    for (int G = tid; G < 96 * 27; G += 512) {
        int j = G / 27;
        int g = G - 27 * j;                          // within-quad index
        unsigned wp = sh4[g];
        float4 o;
        #pragma unroll
        for (int i = 0; i < 4; ++i) {
            int s   = (int)((wp >> (8 * i)) & 255u) - 16;   // d*(4-v)
            int col = j + s;
            float val = xs[(4 * g + i) * LSTR + min(max(col, 0), W - 1)];
            (&o.x)[i] = ((unsigned)col < (unsigned)W) ? val : 0.0f;
        }
        *(float4*)(out + gbase + (size_t)j * WITHIN + 4 * g) = o;
    }

    // ---- ctr output: x[b,c,40,ii,:] -> out[CTR_OFF + ...], done by dd==4,k==0 blocks ----
    if (dd == 4 && k == 0 && tid < 96) {
        int c = tid / 24;
        int q = tid - 24 * c;
        size_t so  = (size_t)((b * NC + c) * NAA + 40) * PLANE + (size_t)ii * W + 4 * q;
        size_t dst = CTR_OFF + (size_t)((b * NC + c) * H + ii) * W + 4 * q;
        *(float4*)(out + dst) = *(const float4*)(x + so);
    }
}

extern "C" void kernel_launch(void* const* d_in, const int* in_sizes, int n_in,
                              void* d_out, int out_size, void* d_ws, size_t ws_size,
                              hipStream_t stream) {
    const float* x    = (const float*)d_in[0];
    const float* mask = (const float*)d_in[1];
    float* out = (float*)d_out;
    dim3 grid(96, ND, 6);   // (ii, dd, b*3+chunk)
    build_cost_kernel<<<grid, 512, 0, stream>>>(x, mask, out);
}

// Round 3
// 261.176 us; speedup vs baseline: 1.0426x; 1.0426x over previous
//
#include <hip/hip_runtime.h>

// cost[b,dd,ii,j,c,uv] = (bounds? x[b,c,uv, ii+d*(4-u), j+d*(4-v)] : 0) * mask[b,uv,ii,j]
// d = dd-4, u=uv/9, v=uv%9.  out = cost (b,9,96,96,324) flat, then ctr = x[:,:,40,:,:].
//
// Block = (ii, dd, b, 32-wide j-chunk): owns a fully contiguous, 64B-aligned
// 41,472-byte output span. LDS staged transposed with shift pre-applied so the
// store phase is pure ds_read_b128 + contiguous float4 nontemporal stores.

#define NAA 81
#define H 96
#define W 96
#define NC 4
#define ND 9
#define PLANE 9216          // 96*96
#define NR 324              // rows = c*81+uv
#define RS 328              // LDS column stride in floats (row dim), %4==0, %32==8
#define JB 32               // j per block
#define OUTROW 31104        // W*NR
#define CTR_OFF 53747712LL  // 2*9*96*96*324

typedef float f32x4 __attribute__((ext_vector_type(4)));

__global__ __launch_bounds__(512)
void build_cost_kernel(const float* __restrict__ x, const float* __restrict__ mask,
                       float* __restrict__ out) {
    __shared__ __align__(16) float xs[JB * RS];   // xs[jj*RS + row]  (41,984 B)
    __shared__ __align__(16) int   lut[2 * NR];   // per row: {xb_or_-1, (mb<<6)|(s+16)}

    const int ii  = blockIdx.x;          // spatial row i
    const int dd  = blockIdx.y;          // disparity index
    const int zz  = blockIdx.z;          // b*3 + j-chunk
    const int b   = zz / 3;
    const int jc  = zz - 3 * b;
    const int j0  = JB * jc;
    const int d   = dd - 4;
    const int tid = threadIdx.x;

    // ---- phase 0: packed per-row LUT (324 rows) ----
    if (tid < NR) {
        int row = tid;                   // row = c*81 + uv
        int c  = row / 81;
        int uv = row - 81 * c;
        int u  = uv / 9;
        int v  = uv - 9 * u;
        int ri = ii + d * (4 - u);
        int xb = ((b * NC + c) * NAA + uv) * PLANE + ri * W;
        int mb = ((b * NAA + uv) * H + ii) * W;
        int s  = d * (4 - v);
        lut[2 * tid]     = ((unsigned)ri < (unsigned)H) ? xb : -1;
        lut[2 * tid + 1] = (mb << 6) | (s + 16);
    }
    __syncthreads();

    // ---- phase 1: stage xs[jj][row] = x[row, ri, j+s] * mask[uv, ii, j] ----
    // item = (row-quad rq, jj); lanes: jj fast -> coalesced global reads,
    // b128 LDS writes at structural-minimum bank occupancy.
    for (int idx = tid; idx < 81 * JB; idx += 512) {
        int rq = idx >> 5;               // row quad 0..80
        int jj = idx & 31;
        int j  = j0 + jj;
        int4 P0 = *(const int4*)&lut[8 * rq];       // rows 4rq, 4rq+1
        int4 P1 = *(const int4*)&lut[8 * rq + 4];   // rows 4rq+2, 4rq+3
        float4 v;
        {
            int xb = P0.x, B = P0.y;
            int s = (B & 63) - 16, col = j + s;
            float xv = x[max(xb, 0) + min(max(col, 0), W - 1)];
            float mv = mask[(B >> 6) + j];
            v.x = (xb >= 0 && (unsigned)col < (unsigned)W) ? xv * mv : 0.0f;
        }
        {
            int xb = P0.z, B = P0.w;
            int s = (B & 63) - 16, col = j + s;
            float xv = x[max(xb, 0) + min(max(col, 0), W - 1)];
            float mv = mask[(B >> 6) + j];
            v.y = (xb >= 0 && (unsigned)col < (unsigned)W) ? xv * mv : 0.0f;
        }
        {
            int xb = P1.x, B = P1.y;
            int s = (B & 63) - 16, col = j + s;
            float xv = x[max(xb, 0) + min(max(col, 0), W - 1)];
            float mv = mask[(B >> 6) + j];
            v.z = (xb >= 0 && (unsigned)col < (unsigned)W) ? xv * mv : 0.0f;
        }
        {
            int xb = P1.z, B = P1.w;
            int s = (B & 63) - 16, col = j + s;
            float xv = x[max(xb, 0) + min(max(col, 0), W - 1)];
            float mv = mask[(B >> 6) + j];
            v.w = (xb >= 0 && (unsigned)col < (unsigned)W) ? xv * mv : 0.0f;
        }
        *(float4*)&xs[jj * RS + 4 * rq] = v;
    }
    __syncthreads();

    // ---- phase 2: contiguous, aligned stores in output order ----
    // out offset = obase + 4*idx (contiguous across the whole block's span);
    // LDS addr = 4*(idx + idx/81) floats (16B-aligned b128 reads).
    const size_t obase = (size_t)((b * ND + dd) * H + ii) * OUTROW + (size_t)j0 * NR;
    for (int idx = tid; idx < 81 * JB; idx += 512) {
        int j = idx / 81;
        f32x4 v = *(const f32x4*)&xs[4 * (idx + j)];
        __builtin_nontemporal_store(v, (f32x4*)(out + obase + 4 * (size_t)idx));
    }

    // ---- ctr output: x[b,c,40,ii,:] (done by dd==4, jc==0 blocks) ----
    if (dd == 4 && jc == 0 && tid < 96) {
        int c = tid / 24;
        int q = tid - 24 * c;
        size_t so  = (size_t)((b * NC + c) * NAA + 40) * PLANE + (size_t)ii * W + 4 * q;
        size_t dst = CTR_OFF + (size_t)((b * NC + c) * H + ii) * W + 4 * q;
        f32x4 cv = *(const f32x4*)(x + so);
        __builtin_nontemporal_store(cv, (f32x4*)(out + dst));
    }
}

extern "C" void kernel_launch(void* const* d_in, const int* in_sizes, int n_in,
                              void* d_out, int out_size, void* d_ws, size_t ws_size,
                              hipStream_t stream) {
    const float* x    = (const float*)d_in[0];
    const float* mask = (const float*)d_in[1];
    float* out = (float*)d_out;
    dim3 grid(96, ND, 6);   // (ii, dd, b*3 + j-chunk)
    build_cost_kernel<<<grid, 512, 0, stream>>>(x, mask, out);
}